// Round 7
// baseline (149.483 us; speedup 1.0000x reference)
//
#include <hip/hip_runtime.h>

// SDPA B=2 H=16 S=2048 D=64 fp32. Two kernels.
//  prep: K,V -> fp16 in MFMA lane-order fragment layout (+ per-tile fp32 V
//        column sums Vpart); mask -> additive bias (-C2 / -1e30).
//  main R7: cooperative-block flash attention, 4 independent blocks/CU.
//        R6 (8-wave block, 1 block/CU) proved correct+spill-free but 66us:
//        8 waves in 2-barrier-per-tile lockstep = zero phase diversity ->
//        ~4x stall vs the ~600cyc/tile dep chain. R7 shrinks blocks to
//        4 waves x 64 q-rows (16 q/wave), grid 32bh x 32qb = 1024 = 4
//        blocks/CU = 4 waves/SIMD in FOUR independent barrier domains that
//        drift out of phase (block A's MFMA fills block B's stalls).
//        Per-wave: ~95 VGPR (safe under the 128 tier for 16 waves/CU).
//        Tile = 32 keys (8KB K+V) in 2-deep shared LDS buffer; each wave
//        DMAs 2KB (2 gll16); per-tile vmem group = 4 -> counted WVC(4),
//        never 0 in-loop; raw s_barrier (no vmcnt(0) drain); asm walls pin
//        issue groups. No K-split combine (wave owns full key range).
// Numerics: Q*scale*log2e folded in, fp16 QK, bias fed as MFMA C operand,
// raw v_exp_f32, v_cvt_pkrtz pack, L via VALU adds. Masked query -> out =
// Vsum/2048 from fp32 Vpart (reference's uniform-softmax branch).

#define Bb 2
#define Hh 16
#define Ss 2048
#define Dd 64

typedef __attribute__((ext_vector_type(8))) _Float16 f16x8;
typedef __attribute__((ext_vector_type(2))) __fp16 fp16x2;
typedef __attribute__((ext_vector_type(4))) float f32x4;

#define C2F (4.0f * 1.44269504088896340736f)
#define SCLF (0.125f * 1.44269504088896340736f)   // folded into Q

// ---------------- prepass ----------------
// Kf frag: id=((bh*32+kt)*8+slot)*64+lane, slot=T*2+c, lane=rl|(g<<4):
//   elem j = K[bh][kt*64+T*16+rl][c*32+g*8+j]
// Vf frag: slot=G*4+n, lane=m|(g<<4):
//   elem j = V[bh][kt*64+G*32+((j>>2)&1)*16+g*4+(j&3)][n*16+m]
__global__ __launch_bounds__(256) void prep_kernel(
    const float* __restrict__ K, const float* __restrict__ V,
    const int* __restrict__ mask,
    ushort* __restrict__ Kf, ushort* __restrict__ Vf,
    float* __restrict__ mb, float* __restrict__ Vpart)
{
    __shared__ ushort tile[4096];
    __shared__ float  part[16][64];
    const int t = threadIdx.x;
    const int blk = blockIdx.x;

    if (blk < 1024) {                       // ---- K tiles (LDS-staged, coalesced) ----
        const int bh = blk >> 5, kt = blk & 31;
        const float* base = K + ((size_t)bh * Ss + kt * 64) * Dd;
        #pragma unroll
        for (int i = 0; i < 4; ++i) {
            const int p  = i * 16 + (t >> 4);
            const int c0 = (t & 15) * 4;
            const float4 f = *(const float4*)(base + (size_t)p * Dd + c0);
            const int T = p >> 4, rl = p & 15;
            const int c = c0 >> 5, g = (c0 & 31) >> 3, j0 = c0 & 7;
            union { _Float16 h[4]; uint2 d; } pk;
            pk.h[0] = (_Float16)f.x; pk.h[1] = (_Float16)f.y;
            pk.h[2] = (_Float16)f.z; pk.h[3] = (_Float16)f.w;
            *(uint2*)&tile[((T * 2 + c) * 64 + (rl | (g << 4))) * 8 + j0] = pk.d;
        }
        __syncthreads();
        uint4* dst = (uint4*)(Kf + (size_t)(bh * 32 + kt) * 4096);
        const uint4* src = (const uint4*)tile;
        dst[t] = src[t]; dst[t + 256] = src[t + 256];
    } else if (blk < 2048) {                // ---- V tiles: register transpose + Vpart ----
        const int bv = blk - 1024;
        const int bh = bv >> 5, kt = bv & 31;
        const float* base = V + ((size_t)bh * Ss + kt * 64) * Dd;
        const int kb4 = (t >> 4) * 4;       // key base 0..60
        const int d0  = (t & 15) * 4;       // d base   0..60 (consecutive t -> coalesced)
        const float4 r0 = *(const float4*)(base + (size_t)(kb4 + 0) * Dd + d0);
        const float4 r1 = *(const float4*)(base + (size_t)(kb4 + 1) * Dd + d0);
        const float4 r2 = *(const float4*)(base + (size_t)(kb4 + 2) * Dd + d0);
        const float4 r3 = *(const float4*)(base + (size_t)(kb4 + 3) * Dd + d0);
        const int G = kb4 >> 5, p5 = kb4 & 31;
        const int tt = p5 >> 4, g = (p5 >> 2) & 3;
        const int j0 = tt * 4;
        const int n = d0 >> 4, m0 = d0 & 15;
        ushort* dstb = Vf + (size_t)(bh * 32 + kt) * 4096;
        const float ra[4][4] = {{r0.x, r1.x, r2.x, r3.x}, {r0.y, r1.y, r2.y, r3.y},
                                {r0.z, r1.z, r2.z, r3.z}, {r0.w, r1.w, r2.w, r3.w}};
        float4 ps;
        #pragma unroll
        for (int dd = 0; dd < 4; ++dd) {
            union { _Float16 h[4]; uint2 d; } pk;
            pk.h[0] = (_Float16)ra[dd][0]; pk.h[1] = (_Float16)ra[dd][1];
            pk.h[2] = (_Float16)ra[dd][2]; pk.h[3] = (_Float16)ra[dd][3];
            const int lane = (m0 + dd) | (g << 4);
            *(uint2*)&dstb[((G * 4 + n) * 64 + lane) * 8 + j0] = pk.d;
            ((float*)&ps)[dd] = (ra[dd][0] + ra[dd][1]) + (ra[dd][2] + ra[dd][3]);
        }
        *(float4*)&part[t >> 4][d0] = ps;   // fp32 partial column sums (4 keys)
        __syncthreads();
        if (t < 64) {
            float acc = 0.f;
            #pragma unroll
            for (int gg = 0; gg < 16; ++gg) acc += part[gg][t];
            Vpart[(size_t)(bh * 32 + kt) * 64 + t] = acc;
        }
    } else {                                // ---- mask -> bias ----
        #pragma unroll
        for (int i = 0; i < 16; ++i) {
            const int idx = i * 256 + t;
            mb[idx] = mask[idx] ? (-C2F) : -1e30f;
        }
    }
}

// async 16B/lane global->LDS (HW adds lane*16 to the wave-uniform LDS base)
static __device__ __forceinline__ void gll16(const void* g, ushort* l) {
    __builtin_amdgcn_global_load_lds(
        (const __attribute__((address_space(1))) void*)g,
        (__attribute__((address_space(3))) void*)l, 16, 0, 0);
}

// ---------------- main (cooperative 4-wave block, 4 blocks/CU) ----------------
__global__ __launch_bounds__(256) void sdpa_main(
    const float* __restrict__ Q, const ushort* __restrict__ Kf,
    const ushort* __restrict__ Vf, const float* __restrict__ mbp,
    const float* __restrict__ Vpart,
    const int* __restrict__ mask, float* __restrict__ out)
{
    // shared 2-deep tile buffer: [buf][K 4KB | V 4KB] = 16 KB per block.
    __shared__ ushort sbuf[2][4096];

    const int t  = threadIdx.x, w = t >> 6, l = t & 63;
    const int lq = l & 15, lg = l >> 4;
    const int bh = blockIdx.x & 31;         // XCD swizzle: one bh -> one L2
    const int qb = blockIdx.x >> 5;         // 0..31
    const int b  = bh >> 4;
    const int q0 = qb * 64 + w * 16;        // wave's 16 q-rows

    const size_t bhS = (size_t)bh * Ss;
    const ushort* kgb = Kf + (size_t)(bh * 32) * 4096;
    const ushort* vgb = Vf + (size_t)(bh * 32) * 4096;
    const float*  mbb = mbp + b * Ss;

    // staging role: wave w DMAs 2KB of each 8KB tile (2 gll16 of 1KB).
    // waves 0,1 -> K halves; waves 2,3 -> V halves.
    const char* sgb = (const char*)(w < 2 ? kgb : vgb) + (w & 1) * 2048 + l * 16;
    const int   sdoff = (w >> 1) * 2048 + (w & 1) * 1024;   // ushort idx, uniform

    // ---- Q fragment: 1 subtile (16 q-rows), fp16, scale*log2e folded ----
    f16x8 qh[2];
    {
        const float* qrow = Q + (bhS + q0 + lq) * Dd + lg * 8;
        #pragma unroll
        for (int c = 0; c < 2; ++c) {
            const float4 f0 = *(const float4*)(qrow + 32 * c);
            const float4 f1 = *(const float4*)(qrow + 32 * c + 4);
            const float qf[8] = {f0.x, f0.y, f0.z, f0.w, f1.x, f1.y, f1.z, f1.w};
            union { _Float16 h[8]; f16x8 v; } pk;
            #pragma unroll
            for (int j = 0; j < 8; ++j) pk.h[j] = (_Float16)(qf[j] * SCLF);
            qh[c] = pk.v;
        }
    }

    f32x4 Oacc[4];
    float lacc = 0.f;
    #pragma unroll
    for (int n = 0; n < 4; ++n) Oacc[n] = f32x4{0.f, 0.f, 0.f, 0.f};

    #define WALL    asm volatile("" ::: "memory")
    #define WVC(n)  asm volatile("s_waitcnt vmcnt(" #n ")" ::: "memory")
    #define BAR     __builtin_amdgcn_s_barrier()

    // wave w stages its 2KB chunk of tile kk into buf (2 vmem ops)
    #define STG(kk, bufsel) do {                                                \
        gll16(sgb + (size_t)(kk) * 128,        &sbuf[bufsel][sdoff]);           \
        gll16(sgb + (size_t)(kk) * 128 + 1024, &sbuf[bufsel][sdoff + 512]);     \
    } while (0)
    #define BIAS(kk, B0, B1) do {                                               \
        B0 = *(const float4*)(mbb + (kk) + lg * 4);                             \
        B1 = *(const float4*)(mbb + (kk) + 16 + lg * 4);                        \
    } while (0)

    #define LDKV(bufsel, KF, VF) do {                                           \
        const ushort* p_ = &sbuf[bufsel][l * 8];                                \
        KF[0] = *(const f16x8*)(p_);                                            \
        KF[1] = *(const f16x8*)(p_ + 512);                                      \
        KF[2] = *(const f16x8*)(p_ + 1024);                                     \
        KF[3] = *(const f16x8*)(p_ + 1536);                                     \
        VF[0] = *(const f16x8*)(p_ + 2048);                                     \
        VF[1] = *(const f16x8*)(p_ + 2560);                                     \
        VF[2] = *(const f16x8*)(p_ + 3072);                                     \
        VF[3] = *(const f16x8*)(p_ + 3584);                                     \
    } while (0)

    // one 32-key tile: QK (bias as MFMA C) -> exp -> L -> pack -> PV
    #define STEP(KF, VF, B0, B1) do {                                           \
        union { uint u32[4]; f16x8 v; } p8_;                                    \
        _Pragma("unroll")                                                       \
        for (int T_ = 0; T_ < 2; ++T_) {                                        \
            const f16x8 k0_ = KF[T_ * 2], k1_ = KF[T_ * 2 + 1];                 \
            const float4 bi_ = (T_ == 0) ? B0 : B1;                             \
            f32x4 sc_ = __builtin_amdgcn_mfma_f32_16x16x32_f16(                 \
                k0_, qh[0], (f32x4){bi_.x, bi_.y, bi_.z, bi_.w}, 0, 0, 0);      \
            sc_ = __builtin_amdgcn_mfma_f32_16x16x32_f16(k1_, qh[1], sc_, 0, 0, 0); \
            const float e0_ = __builtin_amdgcn_exp2f(sc_[0]);                   \
            const float e1_ = __builtin_amdgcn_exp2f(sc_[1]);                   \
            const float e2_ = __builtin_amdgcn_exp2f(sc_[2]);                   \
            const float e3_ = __builtin_amdgcn_exp2f(sc_[3]);                   \
            lacc += (e0_ + e1_) + (e2_ + e3_);                                  \
            union { fp16x2 h; uint u; } pa_, pb_;                               \
            pa_.h = __builtin_amdgcn_cvt_pkrtz(e0_, e1_);                       \
            pb_.h = __builtin_amdgcn_cvt_pkrtz(e2_, e3_);                       \
            p8_.u32[T_ * 2]     = pa_.u;                                        \
            p8_.u32[T_ * 2 + 1] = pb_.u;                                        \
        }                                                                       \
        __builtin_amdgcn_s_setprio(1);                                          \
        _Pragma("unroll")                                                       \
        for (int n_ = 0; n_ < 4; ++n_)                                          \
            Oacc[n_] = __builtin_amdgcn_mfma_f32_16x16x32_f16(p8_.v, VF[n_], Oacc[n_], 0, 0, 0); \
        __builtin_amdgcn_s_setprio(0);                                          \
    } while (0)

    f16x8 kf[4], vf[4];
    float4 a0, a1, b0, b1;

    // ---- prologue: tiles 0 (buf0) and 1 (buf1); vmem groups pinned by walls:
    // [S0 x2, b0 x2][S1 x2, b1 x2] -> 8 outstanding entering the loop.
    WALL;
    STG(0, 0);  BIAS(0, a0, a1);  WALL;
    STG(32, 1); BIAS(32, b0, b1); WALL;

    // ---- K-loop: 64 tiles, unrolled x2. Per tile: wait own 4 oldest vmem
    // (tile t's stage+bias landed), barrier (all 4 waves' chunks landed),
    // ds_read+compute, barrier (all done reading), stage tile t+2 (4 vmem).
    // vmcnt never drains below 4 until the last tile.
    for (int tt = 0; tt < 62; tt += 2) {
        const int kk = tt * 32;
        // tile tt (buf0, biasA)
        WVC(4); BAR; WALL;
        LDKV(0, kf, vf);
        STEP(kf, vf, a0, a1);
        WALL; BAR; WALL;
        STG(kk + 64, 0); BIAS(kk + 64, a0, a1); WALL;
        // tile tt+1 (buf1, biasB)
        WVC(4); BAR; WALL;
        LDKV(1, kf, vf);
        STEP(kf, vf, b0, b1);
        WALL; BAR; WALL;
        STG(kk + 96, 1); BIAS(kk + 96, b0, b1); WALL;
    }
    // tile 62 (buf0): outstanding = {S62x2,b62x2,S63x2,b63x2} -> WVC(4)
    WVC(4); BAR; WALL;
    LDKV(0, kf, vf);
    STEP(kf, vf, a0, a1);
    WALL; BAR; WALL;
    // tile 63 (buf1): drain
    WVC(0); BAR; WALL;
    LDKV(1, kf, vf);
    STEP(kf, vf, b0, b1);

    #undef WALL
    #undef WVC
    #undef BAR
    #undef STG
    #undef BIAS
    #undef LDKV
    #undef STEP

    // ---- epilogue: wave-complete rows, no combine ----
    // Vsum for masked-query rows (fp32 partials from prep)
    float vsum[4] = {0.f, 0.f, 0.f, 0.f};
    const float* vpb = Vpart + (size_t)(bh * 32) * 64;
    #pragma unroll 4
    for (int kt2 = 0; kt2 < 32; ++kt2) {
        #pragma unroll
        for (int n = 0; n < 4; ++n) vsum[n] += vpb[kt2 * 64 + n * 16 + lq];
    }

    const float inv2048 = 1.0f / 2048.0f;
    {
        float L = lacc;
        L += __shfl_xor(L, 16, 64);
        L += __shfl_xor(L, 32, 64);         // lane x holds L[q = x&15]
        const int4 mq4 = *(const int4*)&mask[b * Ss + q0 + lg * 4];
        const int mqa[4] = {mq4.x, mq4.y, mq4.z, mq4.w};
        #pragma unroll
        for (int r = 0; r < 4; ++r) {
            const float invl = 1.0f / __shfl(L, lg * 4 + r, 64);
            float* orow = out + (bhS + q0 + lg * 4 + r) * Dd + lq;
            #pragma unroll
            for (int n = 0; n < 4; ++n)
                orow[16 * n] = mqa[r] ? Oacc[n][r] * invl : vsum[n] * inv2048;
        }
    }
}

extern "C" void kernel_launch(void* const* d_in, const int* in_sizes, int n_in,
                              void* d_out, int out_size, void* d_ws, size_t ws_size,
                              hipStream_t stream) {
    const float* Q    = (const float*)d_in[0];
    const float* K    = (const float*)d_in[1];
    const float* V    = (const float*)d_in[2];
    const int*   mask = (const int*)d_in[3];
    float* out = (float*)d_out;

    ushort* Kf    = (ushort*)d_ws;                        // 8.39 MB
    ushort* Vf    = Kf + (size_t)4194304;                 // 8.39 MB
    float*  mb    = (float*)(Vf + (size_t)4194304);       // 16 KB
    float*  Vpart = mb + 4096;                            // 256 KB

    hipLaunchKernelGGL(prep_kernel, dim3(2049), dim3(256), 0, stream,
                       K, V, mask, Kf, Vf, mb, Vpart);
    hipLaunchKernelGGL(sdpa_main, dim3(1024), dim3(256), 0, stream,
                       Q, Kf, Vf, mb, Vpart, mask, out);
}

// Round 8
// 144.996 us; speedup vs baseline: 1.0309x; 1.0309x over previous
//
#include <hip/hip_runtime.h>

// SDPA B=2 H=16 S=2048 D=64 fp32. Two kernels.
//  prep: K,V -> fp16 in 32x32x16-MFMA lane-order fragment layout (K rows
//        PRE-PERMUTED: swap bits 2<->3 of row index, so QK's D-register order
//        directly matches PV's A-fragment order -- no permlane/shuffle);
//        per-64key-tile fp32 V column sums Vpart; mask -> bias (-C2F/-1e30).
//  main R8: R7 post-mortem: issue-bound on VALU (43% busy, 16q/wave = 8 MFMA
//        per 8KB tile; TLP doubling changed nothing). R8 raises arithmetic
//        intensity: 32x32x16 MFMA (half the instructions, -17% matrix-pipe
//        time) x 32q/wave -> 16 MFMA per 64-key tile; per-SIMD MFMA demand
//        (1033 cyc/iter at 2 waves/SIMD) now exceeds VALU (~440) -> MFMA-
//        bound, floor ~14 us. 4-wave blocks (128q), grid 32bh x 16qb = 512
//        = 2 blocks/CU (2 waves/SIMD, VGPR-tier-safe to 256). 64-key LDS
//        tiles (16KB) double-buffered via global_load_lds (4 chunks/wave);
//        ONE counted vmcnt(4)/iter (never 0), 2 raw s_barriers/iter,
//        uniform vmem ledger (dummy tail stages), bias as MFMA-C operand.
// Numerics: Q*scale*log2e folded, fp16 QK, raw v_exp_f32, cvt_pkrtz pack,
// L via VALU adds + cross-half shfl. Masked query -> Vsum/2048 from Vpart.

#define Bb 2
#define Hh 16
#define Ss 2048
#define Dd 64

typedef __attribute__((ext_vector_type(8))) _Float16 f16x8;
typedef __attribute__((ext_vector_type(2))) __fp16 fp16x2;
typedef __attribute__((ext_vector_type(4))) float f32x4;
typedef __attribute__((ext_vector_type(16))) float f32x16;

#define C2F (4.0f * 1.44269504088896340736f)
#define SCLF (0.125f * 1.44269504088896340736f)   // folded into Q

// ---------------- prepass ----------------
// Kf frag (A-operand, 32x32x16, rows permuted): per bh, 64 subtiles (32 keys):
//   addr = ((bh*64+st)*4 + c)*512 + lane*8 + j   (ushort)
//   lane = rp | (hi<<5), rp = swapbits23(key&31), value = K[st*32+key][c*16+hi*8+j]
// Vf frag (B-operand): slot s = kc*2+dc:
//   addr = ((bh*64+st)*4 + s)*512 + lane*8 + j
//   lane = lh*32 + (d&31), value = V[st*32 + kc*16 + lh*8 + j][dc*32 + (d&31)]
__global__ __launch_bounds__(256) void prep_kernel(
    const float* __restrict__ K, const float* __restrict__ V,
    const int* __restrict__ mask,
    ushort* __restrict__ Kf, ushort* __restrict__ Vf,
    float* __restrict__ mb, float* __restrict__ Vpart)
{
    __shared__ ushort tile[4096];
    __shared__ float  part[16][64];
    const int t = threadIdx.x;
    const int blk = blockIdx.x;

    if (blk < 1024) {                       // ---- K tiles (64 keys/block) ----
        const int bh = blk >> 5, kt = blk & 31;
        const float* base = K + ((size_t)bh * Ss + kt * 64) * Dd;
        #pragma unroll
        for (int i = 0; i < 4; ++i) {
            const int p  = i * 16 + (t >> 4);       // key 0..63
            const int c0 = (t & 15) * 4;            // d base
            const float4 f = *(const float4*)(base + (size_t)p * Dd + c0);
            const int sub = p >> 5, p5 = p & 31;
            const int rp = (p5 & 3) | ((p5 & 4) << 1) | ((p5 & 8) >> 1) | (p5 & 16);
            const int c  = c0 >> 4;                 // 16-d chunk
            const int hi = (c0 >> 3) & 1;
            const int j0 = c0 & 7;
            union { _Float16 h[4]; uint2 d; } pk;
            pk.h[0] = (_Float16)f.x; pk.h[1] = (_Float16)f.y;
            pk.h[2] = (_Float16)f.z; pk.h[3] = (_Float16)f.w;
            *(uint2*)&tile[(((sub * 4 + c) * 64) + (rp | (hi << 5))) * 8 + j0] = pk.d;
        }
        __syncthreads();
        uint4* dst = (uint4*)(Kf + (size_t)(bh * 32 + kt) * 4096);
        const uint4* src = (const uint4*)tile;
        dst[t] = src[t]; dst[t + 256] = src[t + 256];
    } else if (blk < 2048) {                // ---- V tiles: register transpose + Vpart ----
        const int bv = blk - 1024;
        const int bh = bv >> 5, kt = bv & 31;
        const float* base = V + ((size_t)bh * Ss + kt * 64) * Dd;
        const int kb4 = (t >> 4) * 4;       // key base 0..60
        const int d0  = (t & 15) * 4;       // d base   0..60
        const float4 r0 = *(const float4*)(base + (size_t)(kb4 + 0) * Dd + d0);
        const float4 r1 = *(const float4*)(base + (size_t)(kb4 + 1) * Dd + d0);
        const float4 r2 = *(const float4*)(base + (size_t)(kb4 + 2) * Dd + d0);
        const float4 r3 = *(const float4*)(base + (size_t)(kb4 + 3) * Dd + d0);
        const int sub = kb4 >> 5, kc = (kb4 >> 4) & 1, lh = (kb4 >> 3) & 1;
        const int j0 = kb4 & 7;
        const int dc = d0 >> 5;
        const int slot = kc * 2 + dc;
        ushort* dstb = Vf + (size_t)(bh * 32 + kt) * 4096;
        const float ra[4][4] = {{r0.x, r1.x, r2.x, r3.x}, {r0.y, r1.y, r2.y, r3.y},
                                {r0.z, r1.z, r2.z, r3.z}, {r0.w, r1.w, r2.w, r3.w}};
        float4 ps;
        #pragma unroll
        for (int dd = 0; dd < 4; ++dd) {
            union { _Float16 h[4]; uint2 d; } pk;
            pk.h[0] = (_Float16)ra[dd][0]; pk.h[1] = (_Float16)ra[dd][1];
            pk.h[2] = (_Float16)ra[dd][2]; pk.h[3] = (_Float16)ra[dd][3];
            const int lane = (lh << 5) | ((d0 + dd) & 31);
            *(uint2*)&dstb[(((sub * 4 + slot) * 64) + lane) * 8 + j0] = pk.d;
            ((float*)&ps)[dd] = (ra[dd][0] + ra[dd][1]) + (ra[dd][2] + ra[dd][3]);
        }
        *(float4*)&part[t >> 4][d0] = ps;   // fp32 partial column sums (4 keys)
        __syncthreads();
        if (t < 64) {
            float acc = 0.f;
            #pragma unroll
            for (int gg = 0; gg < 16; ++gg) acc += part[gg][t];
            Vpart[(size_t)(bh * 32 + kt) * 64 + t] = acc;
        }
    } else {                                // ---- mask -> bias ----
        #pragma unroll
        for (int i = 0; i < 16; ++i) {
            const int idx = i * 256 + t;
            mb[idx] = mask[idx] ? (-C2F) : -1e30f;
        }
    }
}

// async 16B/lane global->LDS (HW adds lane*16 to the wave-uniform LDS base)
static __device__ __forceinline__ void gll16(const void* g, ushort* l) {
    __builtin_amdgcn_global_load_lds(
        (const __attribute__((address_space(1))) void*)g,
        (__attribute__((address_space(3))) void*)l, 16, 0, 0);
}

// ---------------- main (32x32 MFMA, 32q/wave, cooperative 4-wave block) ----------------
__global__ __launch_bounds__(256) void sdpa_main(
    const float* __restrict__ Q, const ushort* __restrict__ Kf,
    const ushort* __restrict__ Vf, const float* __restrict__ mbp,
    const float* __restrict__ Vpart,
    const int* __restrict__ mask, float* __restrict__ out)
{
    // 2-deep 64-key tile buffer: [buf][K sub0|K sub1|V sub0|V sub1] = 2x16 KB.
    __shared__ ushort sbuf[2][8192];

    const int t  = threadIdx.x, w = t >> 6, l = t & 63;
    const int ql = l & 31, h = l >> 5;
    const int bh = blockIdx.x & 31;         // XCD swizzle: one bh -> one L2
    const int qb = blockIdx.x >> 5;         // 0..15
    const int b  = bh >> 4;
    const int q0 = qb * 128 + w * 32;       // wave's 32 q-rows

    const size_t bhS = (size_t)bh * Ss;
    const ushort* kgb = Kf + (size_t)bh * 131072;
    const ushort* vgb = Vf + (size_t)bh * 131072;
    const float*  mbb = mbp + b * Ss;

    // staging role: wave w DMAs 4KB of each 16KB tile (4 gll16 of 1KB).
    // w0: K sub0, w1: K sub1, w2: V sub0, w3: V sub1 (global layout matches).
    const ushort* sgb = (w < 2 ? kgb : vgb) + (w & 1) * 2048 + (size_t)l * 8;
    ushort* sdst0 = &sbuf[0][w * 2048];
    ushort* sdst1 = &sbuf[1][w * 2048];

    // ---- Q fragments (B-operand): qh[c] = Q[q0+ql][c*16 + h*8 + 0..7]*SCLF ----
    f16x8 qh[4];
    #pragma unroll
    for (int c = 0; c < 4; ++c) {
        const float* qp = Q + (bhS + q0 + ql) * Dd + c * 16 + h * 8;
        const float4 f0 = *(const float4*)(qp);
        const float4 f1 = *(const float4*)(qp + 4);
        const float qf[8] = {f0.x, f0.y, f0.z, f0.w, f1.x, f1.y, f1.z, f1.w};
        union { _Float16 hh[8]; f16x8 v; } pk;
        #pragma unroll
        for (int j = 0; j < 8; ++j) pk.hh[j] = (_Float16)(qf[j] * SCLF);
        qh[c] = pk.v;
    }

    f32x16 Oacc[2] = {};
    float lacc = 0.f;

    union bbu { float4 q4[4]; f32x16 v; };
    bbu bbA, bbB;                           // bias-as-C for sub0/sub1

    #define WALL    asm volatile("" ::: "memory")
    #define WVC(n)  asm volatile("s_waitcnt vmcnt(" #n ")" ::: "memory")
    #define BAR     __builtin_amdgcn_s_barrier()

    #define STG(tt, dstb) do {                                                  \
        const ushort* sp_ = sgb + (size_t)(tt) * 4096;                          \
        gll16(sp_,        dstb);                                                \
        gll16(sp_ + 512,  dstb + 512);                                          \
        gll16(sp_ + 1024, dstb + 1024);                                         \
        gll16(sp_ + 1536, dstb + 1536);                                         \
    } while (0)

    // bias element j = mb[kbase + (j>>3)*16 + 8h + (j&7)]  (8 float4 loads)
    #define BIAS(tt) do {                                                       \
        const float* mpA_ = mbb + (tt) * 64 + 8 * h;                            \
        bbA.q4[0] = *(const float4*)(mpA_);                                     \
        bbA.q4[1] = *(const float4*)(mpA_ + 4);                                 \
        bbA.q4[2] = *(const float4*)(mpA_ + 16);                                \
        bbA.q4[3] = *(const float4*)(mpA_ + 20);                                \
        const float* mpB_ = mpA_ + 32;                                          \
        bbB.q4[0] = *(const float4*)(mpB_);                                     \
        bbB.q4[1] = *(const float4*)(mpB_ + 4);                                 \
        bbB.q4[2] = *(const float4*)(mpB_ + 16);                                \
        bbB.q4[3] = *(const float4*)(mpB_ + 20);                                \
    } while (0)

    // one 32-key subtile: QK (4 chained 32x32 MFMA, bias in C) -> exp -> L ->
    // pack (register order IS the PV A-frag order thanks to prep's K row
    // permutation) -> PV (4 MFMA).
    #define SUB(bufp, sub, CC) do {                                             \
        const ushort* kp_ = (bufp) + (sub) * 2048 + l * 8;                      \
        const f16x8 k0_ = *(const f16x8*)(kp_);                                 \
        const f16x8 k1_ = *(const f16x8*)(kp_ + 512);                           \
        const f16x8 k2_ = *(const f16x8*)(kp_ + 1024);                          \
        const f16x8 k3_ = *(const f16x8*)(kp_ + 1536);                          \
        f32x16 sc_ = __builtin_amdgcn_mfma_f32_32x32x16_f16(k0_, qh[0], CC.v, 0, 0, 0); \
        sc_ = __builtin_amdgcn_mfma_f32_32x32x16_f16(k1_, qh[1], sc_, 0, 0, 0); \
        sc_ = __builtin_amdgcn_mfma_f32_32x32x16_f16(k2_, qh[2], sc_, 0, 0, 0); \
        sc_ = __builtin_amdgcn_mfma_f32_32x32x16_f16(k3_, qh[3], sc_, 0, 0, 0); \
        float e_[16];                                                           \
        _Pragma("unroll")                                                       \
        for (int j_ = 0; j_ < 16; ++j_) e_[j_] = __builtin_amdgcn_exp2f(sc_[j_]); \
        lacc += (((e_[0] + e_[1]) + (e_[2] + e_[3])) + ((e_[4] + e_[5]) + (e_[6] + e_[7]))) \
              + (((e_[8] + e_[9]) + (e_[10] + e_[11])) + ((e_[12] + e_[13]) + (e_[14] + e_[15]))); \
        union { uint u[4]; f16x8 v; } pa_, pb_;                                 \
        { union { fp16x2 hh; uint u; } c_;                                      \
          c_.hh = __builtin_amdgcn_cvt_pkrtz(e_[0], e_[1]);  pa_.u[0] = c_.u;   \
          c_.hh = __builtin_amdgcn_cvt_pkrtz(e_[2], e_[3]);  pa_.u[1] = c_.u;   \
          c_.hh = __builtin_amdgcn_cvt_pkrtz(e_[4], e_[5]);  pa_.u[2] = c_.u;   \
          c_.hh = __builtin_amdgcn_cvt_pkrtz(e_[6], e_[7]);  pa_.u[3] = c_.u;   \
          c_.hh = __builtin_amdgcn_cvt_pkrtz(e_[8], e_[9]);  pb_.u[0] = c_.u;   \
          c_.hh = __builtin_amdgcn_cvt_pkrtz(e_[10], e_[11]); pb_.u[1] = c_.u;  \
          c_.hh = __builtin_amdgcn_cvt_pkrtz(e_[12], e_[13]); pb_.u[2] = c_.u;  \
          c_.hh = __builtin_amdgcn_cvt_pkrtz(e_[14], e_[15]); pb_.u[3] = c_.u; }\
        const ushort* vp_ = (bufp) + 4096 + (sub) * 2048 + l * 8;               \
        const f16x8 v00_ = *(const f16x8*)(vp_);                                \
        const f16x8 v01_ = *(const f16x8*)(vp_ + 512);                          \
        const f16x8 v10_ = *(const f16x8*)(vp_ + 1024);                         \
        const f16x8 v11_ = *(const f16x8*)(vp_ + 1536);                         \
        __builtin_amdgcn_s_setprio(1);                                          \
        Oacc[0] = __builtin_amdgcn_mfma_f32_32x32x16_f16(pa_.v, v00_, Oacc[0], 0, 0, 0); \
        Oacc[0] = __builtin_amdgcn_mfma_f32_32x32x16_f16(pb_.v, v10_, Oacc[0], 0, 0, 0); \
        Oacc[1] = __builtin_amdgcn_mfma_f32_32x32x16_f16(pa_.v, v01_, Oacc[1], 0, 0, 0); \
        Oacc[1] = __builtin_amdgcn_mfma_f32_32x32x16_f16(pb_.v, v11_, Oacc[1], 0, 0, 0); \
        __builtin_amdgcn_s_setprio(0);                                          \
    } while (0)

    // ---- prologue: stage tile 0 (buf0), bias(0), stage tile 1 (buf1) ----
    // outstanding vmem: [st0 4][b0 8][st1 4] = 16.
    WALL;
    STG(0, sdst0); WALL;
    BIAS(0);       WALL;
    STG(1, sdst1); WALL;

    // ---- K-loop: 32 tiles of 64 keys. Steady ledger entering iter i:
    // [st(i) 4][b(i) 8][st(i+1) 4]; WVC(4) drains st(i)+b(i), leaves st(i+1).
    // Tail iterations issue harmless dummy stages/bias to keep ledger uniform.
    for (int i = 0; i < 32; ++i) {
        ushort* bufp = (i & 1) ? &sbuf[1][0] : &sbuf[0][0];
        ushort* sd   = (i & 1) ? sdst1 : sdst0;
        WVC(4); BAR; WALL;
        SUB(bufp, 0, bbA);
        SUB(bufp, 1, bbB);
        WALL;
        BIAS((i + 1) & 31);                 // next tile's bias (regs free now)
        WALL; BAR; WALL;
        STG((i + 2) & 31, sd);              // into the buf just consumed
        WALL;
    }
    WVC(0);                                 // drain tail dummies before exit

    #undef WALL
    #undef WVC
    #undef BAR
    #undef STG
    #undef BIAS
    #undef SUB

    // ---- epilogue: wave-complete rows, no combine ----
    float Lf = lacc + __shfl_xor(lacc, 32, 64);   // both key-halves -> L[q=ql]

    // Vsum (masked-query rows): d = dc*32 + ql
    float vs0 = 0.f, vs1 = 0.f;
    const float* vpb = Vpart + (size_t)(bh * 32) * 64;
    #pragma unroll 4
    for (int kt2 = 0; kt2 < 32; ++kt2) {
        vs0 += vpb[kt2 * 64 + ql];
        vs1 += vpb[kt2 * 64 + 32 + ql];
    }

    const int* mrow = mask + b * Ss + q0;
    const int4 m0 = *(const int4*)(mrow + 4 * h);
    const int4 m1 = *(const int4*)(mrow + 8 + 4 * h);
    const int4 m2 = *(const int4*)(mrow + 16 + 4 * h);
    const int4 m3 = *(const int4*)(mrow + 24 + 4 * h);
    const int mqa[16] = {m0.x, m0.y, m0.z, m0.w, m1.x, m1.y, m1.z, m1.w,
                         m2.x, m2.y, m2.z, m2.w, m3.x, m3.y, m3.z, m3.w};

    const float inv2048 = 1.0f / 2048.0f;
    #pragma unroll
    for (int j = 0; j < 16; ++j) {
        const int qr = (j & 3) + 8 * (j >> 2) + 4 * h;   // C/D row (q)
        const float Lq = __shfl(Lf, qr, 64);
        const float invl = 1.0f / Lq;
        const int mq = mqa[j];
        float* op = out + (bhS + q0 + qr) * Dd + ql;
        op[0]  = mq ? Oacc[0][j] * invl : vs0 * inv2048;
        op[32] = mq ? Oacc[1][j] * invl : vs1 * inv2048;
    }
}

extern "C" void kernel_launch(void* const* d_in, const int* in_sizes, int n_in,
                              void* d_out, int out_size, void* d_ws, size_t ws_size,
                              hipStream_t stream) {
    const float* Q    = (const float*)d_in[0];
    const float* K    = (const float*)d_in[1];
    const float* V    = (const float*)d_in[2];
    const int*   mask = (const int*)d_in[3];
    float* out = (float*)d_out;

    ushort* Kf    = (ushort*)d_ws;                        // 8.39 MB
    ushort* Vf    = Kf + (size_t)4194304;                 // 8.39 MB
    float*  mb    = (float*)(Vf + (size_t)4194304);       // 16 KB
    float*  Vpart = mb + 4096;                            // 256 KB

    hipLaunchKernelGGL(prep_kernel, dim3(2049), dim3(256), 0, stream,
                       K, V, mask, Kf, Vf, mb, Vpart);
    hipLaunchKernelGGL(sdpa_main, dim3(512), dim3(256), 0, stream,
                       Q, Kf, Vf, mb, Vpart, mask, out);
}